// Round 11
// baseline (95.578 us; speedup 1.0000x reference)
//
#include <hip/hip_runtime.h>
#include <math.h>

#define D 512
#define TEMP_INV 14.285714285714286f  // 1/0.07
#define NBT 32                         // 4096 / 128 tile grid dim
#define NBLK (NBT * (NBT + 1) / 2)     // 528 upper-tri tiles

typedef int v8i __attribute__((ext_vector_type(8)));     // 32 fp8 elems
typedef float f32x16 __attribute__((ext_vector_type(16)));

// global->LDS direct DMA, 16 B per lane. LDS dest = wave-uniform base + lane*16.
#define GLDS16(g, l) __builtin_amdgcn_global_load_lds(                         \
    (const __attribute__((address_space(1))) unsigned int*)(g),                \
    (__attribute__((address_space(3))) unsigned int*)(l), 16, 0, 0)

// ws layout (float units):
//   [0]              neg_sum accumulator (float atomic)
//   [1]              completion counter (int atomic)
//   [64 .. 64+2048)  p values (positive-pair logits), written via atomic stores
//   [4096 .. )       efp8: normalized fp8(e4m3) matrix [4096][512] (2 MB)

// One wave per row: rsqrt(sum sq), scale, cvt to fp8 e4m3 (OCP), store packed.
__global__ void infonce_norm_cast_kernel(const float* __restrict__ emb,
                                         float* __restrict__ ws, int nrows) {
    if (blockIdx.x == 0 && threadIdx.x == 0) {
        ws[0] = 0.0f;        // neg_sum
        ((int*)ws)[1] = 0;   // completion counter
    }
    unsigned int* __restrict__ ef = (unsigned int*)(ws + 4096);
    const int lane = threadIdx.x & 63;
    const int wave = threadIdx.x >> 6;
    const int row = blockIdx.x * 4 + wave;
    if (row >= nrows) return;
    const float* r = emb + (size_t)row * D;
    float4 v1 = *(const float4*)&r[lane * 4];
    float4 v2 = *(const float4*)&r[256 + lane * 4];
    float s = v1.x * v1.x + v1.y * v1.y + v1.z * v1.z + v1.w * v1.w
            + v2.x * v2.x + v2.y * v2.y + v2.z * v2.z + v2.w * v2.w;
    #pragma unroll
    for (int off = 32; off > 0; off >>= 1) s += __shfl_down(s, off, 64);
    const float rn = __shfl(rsqrtf(s), 0, 64);

    unsigned int p0 = __builtin_amdgcn_cvt_pk_fp8_f32(v1.x * rn, v1.y * rn, 0, false);
    p0 = __builtin_amdgcn_cvt_pk_fp8_f32(v1.z * rn, v1.w * rn, p0, true);
    unsigned int p1 = __builtin_amdgcn_cvt_pk_fp8_f32(v2.x * rn, v2.y * rn, 0, false);
    p1 = __builtin_amdgcn_cvt_pk_fp8_f32(v2.z * rn, v2.w * rn, p1, true);
    ef[(size_t)row * 128 + lane] = p0;        // bytes [lane*4, +4)
    ef[(size_t)row * 128 + 64 + lane] = p1;   // bytes [256 + lane*4, +4)
}

// Upper-triangular 128x128 tiles (528 blocks), 256 threads (4 waves). fp8:
// both FULL panels (128 x 512 B = 64 KB each) in LDS, single-shot staging
// (32 glds/wave, ONE vmcnt drain at ONE barrier), 32 mfma_scale per wave.
// R10 hot loop unchanged. NEW: loss fused fence-free — pvals/neg written via
// agent-scope atomics (performed at coherent point), explicit s_waitcnt(0)
// orders them before the completion-counter add, last block reads via
// agent-scope atomic loads. No wbl2/inv anywhere (R5 lesson).
__global__ __launch_bounds__(256, 1) void infonce_sim_kernel(
        const int* __restrict__ labels, float* __restrict__ ws,
        float* __restrict__ out) {
    // contiguous-per-XCD chunking (528 % 8 == 0)
    const int grp = gridDim.x >> 3;
    const int tile = (blockIdx.x & 7) * grp + (blockIdx.x >> 3);
    // triangular decode: row-major over {(bi,bj): bj>=bi}
    int rem = tile, bi = 0;
    while (rem >= (NBT - bi)) { rem -= (NBT - bi); ++bi; }
    const int bj = bi + rem;

    const unsigned char* __restrict__ efp8 = (const unsigned char*)(ws + 4096);
    float* __restrict__ pvals = ws + 64;

    __shared__ __align__(16) unsigned char As[128 * 512];  // 64 KB
    __shared__ __align__(16) unsigned char Bs[128 * 512];  // 64 KB
    __shared__ int lab_row[128], lab_col[128];
    __shared__ float red[4];
    __shared__ int is_last;

    const int t = threadIdx.x;
    const int w = t >> 6, l = t & 63;
    const int wy = w >> 1, wx = w & 1;
    const int ln = l & 31;   // row/col within a 32x32 sub-tile
    const int hi = l >> 5;   // k-half selector within one MFMA's K=64
    const int rowA0 = bi * 128, rowB0 = bj * 128;

    if (t < 128) lab_row[t] = labels[(rowA0 + t) >> 1];
    else lab_col[t - 128] = labels[(rowB0 + t - 128) >> 1];

    // ---- single-shot staging: wave w stages rows [w*32, w*32+32) of A and B.
    // glds s covers 2 rows (64 lanes x 16 B = 1 KB). Lane l: r = w*32 + s*2
    // + (l>>5), slot cl = l&31, global chunk c = (cl&24)|((cl^r)&7).
    {
        const int rl = l >> 5, cl = l & 31;
        const unsigned char* gA = efp8 + ((size_t)rowA0 << 9);
        const unsigned char* gB = efp8 + ((size_t)rowB0 << 9);
        #pragma unroll
        for (int s = 0; s < 16; ++s) {
            const int r = w * 32 + s * 2 + rl;
            const int c = (cl & 24) | ((cl ^ r) & 7);
            const size_t gofs = ((size_t)r << 9) + c * 16;
            const int lbase = (w * 32 + s * 2) * 512;  // wave-uniform
            GLDS16(gA + gofs, &As[lbase]);
            GLDS16(gB + gofs, &Bs[lbase]);
        }
    }

    f32x16 acc[4] = {};  // [ma*2+nb]

    __syncthreads();  // single vmcnt(0) drain: 32 glds/wave in flight

    #pragma unroll
    for (int kk = 0; kk < 8; ++kk) {
        const int c0 = kk * 4 + hi * 2, c1 = c0 + 1;
        union { v8i v; uint4 q[2]; } ua[2], ub[2];
        #pragma unroll
        for (int ma = 0; ma < 2; ++ma) {
            const int ra = wy * 64 + ma * 32 + ln;
            ua[ma].q[0] = *(const uint4*)&As[ra * 512 + (((c0 & 24) | ((c0 ^ ra) & 7)) << 4)];
            ua[ma].q[1] = *(const uint4*)&As[ra * 512 + (((c1 & 24) | ((c1 ^ ra) & 7)) << 4)];
        }
        #pragma unroll
        for (int nb = 0; nb < 2; ++nb) {
            const int rb = wx * 64 + nb * 32 + ln;
            ub[nb].q[0] = *(const uint4*)&Bs[rb * 512 + (((c0 & 24) | ((c0 ^ rb) & 7)) << 4)];
            ub[nb].q[1] = *(const uint4*)&Bs[rb * 512 + (((c1 & 24) | ((c1 ^ rb) & 7)) << 4)];
        }
        #pragma unroll
        for (int ma = 0; ma < 2; ++ma)
            #pragma unroll
            for (int nb = 0; nb < 2; ++nb)
                acc[ma * 2 + nb] = __builtin_amdgcn_mfma_scale_f32_32x32x64_f8f6f4(
                    ua[ma].v, ub[nb].v, acc[ma * 2 + nb], 0, 0,
                    0, 0x7F7F7F7F, 0, 0x7F7F7F7F);  // fp8/fp8, scales = 1.0
    }

    // Epilogue: 32x32 C/D layout: col = lane&31, row = (reg&3)+8*(reg>>2)+4*(lane>>5).
    float neg_local = 0.0f;
    #pragma unroll
    for (int ma = 0; ma < 2; ++ma) {
        #pragma unroll
        for (int nb = 0; nb < 2; ++nb) {
            const f32x16 a = acc[ma * 2 + nb];
            #pragma unroll
            for (int reg = 0; reg < 16; ++reg) {
                const int rrow = (reg & 3) + 8 * (reg >> 2) + 4 * hi;
                const int li = wy * 64 + ma * 32 + rrow;
                const int lj = wx * 64 + nb * 32 + ln;
                const int i = rowA0 + li;
                const int j = rowB0 + lj;
                const float S = a[reg] * TEMP_INV;
                if (j > i) {
                    if (lab_row[li] != lab_col[lj]) neg_local += __expf(S);
                    if (!(i & 1) && j == i + 1)  // atomic store -> coherent point
                        __hip_atomic_store(&pvals[i >> 1], S, __ATOMIC_RELAXED,
                                           __HIP_MEMORY_SCOPE_AGENT);
                }
            }
        }
    }

    float s = neg_local;
    #pragma unroll
    for (int off = 32; off > 0; off >>= 1) s += __shfl_down(s, off, 64);
    if (l == 0) red[w] = s;
    __syncthreads();  // drains vmcnt -> all this block's pval stores performed

    if (t == 0) {
        atomicAdd(ws, red[0] + red[1] + red[2] + red[3]);
        __builtin_amdgcn_s_waitcnt(0);  // neg atomic + pvals performed before...
        const int prev = __hip_atomic_fetch_add((int*)ws + 1, 1,
                                                __ATOMIC_RELAXED,
                                                __HIP_MEMORY_SCOPE_AGENT);
        is_last = (prev == NBLK - 1);
    }
    __syncthreads();
    if (!is_last) return;

    // ---- last block: all 528 counter-adds observed -> all pvals/neg
    // performed at the coherent point; read them back with agent-scope
    // atomic loads (bypass stale caches). No fences needed.
    const float neg = __hip_atomic_load(ws, __ATOMIC_RELAXED,
                                        __HIP_MEMORY_SCOPE_AGENT);
    float local = 0.0f;
    for (int k = t; k < 2048; k += 256) {
        const float p = __hip_atomic_load(&pvals[k], __ATOMIC_RELAXED,
                                          __HIP_MEMORY_SCOPE_AGENT);
        local += logf(__expf(p) + neg) - p;
    }
    float ls = local;
    #pragma unroll
    for (int off = 32; off > 0; off >>= 1) ls += __shfl_down(ls, off, 64);
    if (l == 0) red[w] = ls;
    __syncthreads();
    if (t == 0) out[0] = (red[0] + red[1] + red[2] + red[3]) / 2048.0f;
}

extern "C" void kernel_launch(void* const* d_in, const int* in_sizes, int n_in,
                              void* d_out, int out_size, void* d_ws, size_t ws_size,
                              hipStream_t stream) {
    const float* emb = (const float*)d_in[0];
    const int* labels = (const int*)d_in[1];
    float* out = (float*)d_out;
    float* ws = (float*)d_ws;

    const int ntot = in_sizes[0] / D;  // 4096

    infonce_norm_cast_kernel<<<ntot / 4, 256, 0, stream>>>(emb, ws, ntot);
    infonce_sim_kernel<<<NBLK, 256, 0, stream>>>(labels, ws, out);
}